// Round 4
// baseline (292.759 us; speedup 1.0000x reference)
//
#include <hip/hip_runtime.h>
#include <hip/hip_cooperative_groups.h>
#include <math.h>

namespace cg = cooperative_groups;

#define HW     512
#define CH     16
#define PIXELS (HW * HW)          // 262144 = 2^18
#define BATCH  8
#define NBLK   1024               // 4 blocks/CU on 256 CUs, co-resident
#define SLICES 128                // NBLK / BATCH slices per batch

typedef float f32x4 __attribute__((ext_vector_type(4)));

// ---------------------------------------------------------------------------
// Single cooperative kernel:
//   phase 1 : per-block partial channel sums (block bid: batch=bid&7, slice=bid>>3)
//   grid.sync()
//   phase 2a: each block computes its batch's rotation params from partials
//   phase 2b: bilinear rotate; block owns 4 output rows of image (bid&7);
//             XCD (bid%8) therefore owns one whole image -> L2-local overlap.
// ---------------------------------------------------------------------------
__global__ __launch_bounds__(256, 4) void fused_rotation_kernel(
        const float* __restrict__ x,
        const float* __restrict__ w_angle,
        const float* __restrict__ b_angle,
        float* __restrict__ partial,
        float* __restrict__ out) {
    const int bid = blockIdx.x;
    const int tid = threadIdx.x;
    const int b   = bid & 7;            // batch / XCD
    const int s   = bid >> 3;           // slice (phase 1) / row-band (phase 2)

    __shared__ float swave[4][CH];
    __shared__ float red[16][CH];
    __shared__ float mean_s[CH];
    __shared__ float prm[4];

    // ---------------- phase 1: partial sums ----------------
    {
        const float4* xp = (const float4*)(x + (size_t)b * PIXELS * CH);
        int idx = s * 8192 + tid;        // 8192 float4 per slice
        float4 acc = make_float4(0.f, 0.f, 0.f, 0.f);
#pragma unroll 8
        for (int k = 0; k < 32; ++k) {
            float4 v = xp[idx + k * 256];
            acc.x += v.x; acc.y += v.y; acc.z += v.z; acc.w += v.w;
        }
        // reduce across lanes sharing (lane & 3); channel quad = lane&3
        for (int off = 4; off < 64; off <<= 1) {
            acc.x += __shfl_xor(acc.x, off);
            acc.y += __shfl_xor(acc.y, off);
            acc.z += __shfl_xor(acc.z, off);
            acc.w += __shfl_xor(acc.w, off);
        }
        const int wave = tid >> 6;
        const int lane = tid & 63;
        if (lane < 4) {
            swave[wave][lane * 4 + 0] = acc.x;
            swave[wave][lane * 4 + 1] = acc.y;
            swave[wave][lane * 4 + 2] = acc.z;
            swave[wave][lane * 4 + 3] = acc.w;
        }
        __syncthreads();
        if (tid < CH) {
            float t = swave[0][tid] + swave[1][tid]
                    + swave[2][tid] + swave[3][tid];
            partial[(size_t)((b * SLICES + s) * CH) + tid] = t;
        }
        __threadfence();   // make partials device-visible before grid sync
    }

    cg::this_grid().sync();

    // ---------------- phase 2a: per-batch params (redundant per block) -----
    {
        const int c  = tid & 15;
        const int sg = tid >> 4;         // 0..15
        float sum8 = 0.f;
#pragma unroll
        for (int j = 0; j < 8; ++j)
            sum8 += partial[(size_t)((b * SLICES + sg + 16 * j) * CH) + c];
        red[sg][c] = sum8;
        __syncthreads();
        if (tid < CH) {
            float m = 0.f;
#pragma unroll
            for (int g = 0; g < 16; ++g) m += red[g][tid];
            mean_s[tid] = m * (1.0f / (float)PIXELS);
        }
        __syncthreads();
        if (tid == 0) {
            float dot = b_angle[0];
#pragma unroll
            for (int c2 = 0; c2 < CH; ++c2) dot += mean_s[c2] * w_angle[c2];
            float tn = tanhf(dot);
            const float pi = 3.14159265358979323846f;
            float ang = fminf(fmaxf(tn * pi, -pi), pi);
            float cs = cosf(ang);
            float sn = sinf(ang);
            prm[0] = cs;
            prm[1] = sn;
            prm[2] = (511.0f - (cs * 511.0f - sn * 511.0f)) * 0.5f;  // x_off
            prm[3] = (511.0f - (sn * 511.0f + cs * 511.0f)) * 0.5f;  // y_off
        }
        __syncthreads();
    }

    const float cs = prm[0];
    const float sn = prm[1];
    const float xo = prm[2];
    const float yo = prm[3];

    // ---------------- phase 2b: rotate 4 output rows ----------------
    const float4* basex = (const float4*)x   + (size_t)b * PIXELS * 4 + (tid & 3);
    float4*       outp  = (float4*)out       + (size_t)b * PIXELS * 4
                                             + (size_t)s * 8192;      // r0*512*4
    const int r0 = s * 4;

#pragma unroll 2
    for (int it = 0; it < 32; ++it) {
        const int local = it * 256 + tid;      // 0..8191
        const int pl    = local >> 2;          // pixel within band, 0..2047
        const int oy    = r0 + (pl >> 9);
        const int ox    = pl & (HW - 1);

        const float fx = (float)ox;
        const float fy = (float)oy;
        const float ix = cs * fx - sn * fy + xo;
        const float iy = sn * fx + cs * fy + yo;
        const float x0f = floorf(ix);
        const float y0f = floorf(iy);
        const float wx = ix - x0f;
        const float wy = iy - y0f;
        const int x0 = (int)x0f;
        const int y0 = (int)y0f;

        float4 v00, v01, v10, v11;
        if (x0 >= 0 && y0 >= 0 && x0 < HW - 1 && y0 < HW - 1) {
            const float4* row0 = basex + (size_t)y0 * (HW * 4);
            v00 = row0[(size_t)x0 * 4];
            v01 = row0[(size_t)(x0 + 1) * 4];
            const float4* row1 = row0 + HW * 4;
            v10 = row1[(size_t)x0 * 4];
            v11 = row1[(size_t)(x0 + 1) * 4];
        } else {
            auto read = [&](int yy, int xx) -> float4 {
                if ((unsigned)xx < (unsigned)HW && (unsigned)yy < (unsigned)HW)
                    return basex[((size_t)yy * HW + xx) * 4];
                return make_float4(0.f, 0.f, 0.f, 0.f);
            };
            v00 = read(y0,     x0);
            v01 = read(y0,     x0 + 1);
            v10 = read(y0 + 1, x0);
            v11 = read(y0 + 1, x0 + 1);
        }

        const float wx1 = 1.0f - wx;
        const float wy1 = 1.0f - wy;
        f32x4 r;
        r.x = (v00.x * wx1 + v01.x * wx) * wy1 + (v10.x * wx1 + v11.x * wx) * wy;
        r.y = (v00.y * wx1 + v01.y * wx) * wy1 + (v10.y * wx1 + v11.y * wx) * wy;
        r.z = (v00.z * wx1 + v01.z * wx) * wy1 + (v10.z * wx1 + v11.z * wx) * wy;
        r.w = (v00.w * wx1 + v01.w * wx) * wy1 + (v10.w * wx1 + v11.w * wx) * wy;

        __builtin_nontemporal_store(r, (f32x4*)(outp + local));
    }
}

extern "C" void kernel_launch(void* const* d_in, const int* in_sizes, int n_in,
                              void* d_out, int out_size, void* d_ws, size_t ws_size,
                              hipStream_t stream) {
    const float* x       = (const float*)d_in[0];
    const float* w_angle = (const float*)d_in[1];
    const float* b_angle = (const float*)d_in[2];
    float* out     = (float*)d_out;
    float* partial = (float*)d_ws;     // BATCH*SLICES*CH = 16384 floats

    void* args[] = { (void*)&x, (void*)&w_angle, (void*)&b_angle,
                     (void*)&partial, (void*)&out };
    hipLaunchCooperativeKernel((const void*)fused_rotation_kernel,
                               dim3(NBLK), dim3(256), args, 0, stream);
}

// Round 5
// 101.625 us; speedup vs baseline: 2.8808x; 2.8808x over previous
//
#include <hip/hip_runtime.h>
#include <math.h>

#define HW     512
#define CH     16
#define PIXELS (HW * HW)          // 262144 = 2^18
#define BATCH  8
#define SLICES 128                // reduce blocks per batch
#define NBLK   (BATCH * SLICES)   // 1024

typedef float f32x4 __attribute__((ext_vector_type(4)));

// ---------------------------------------------------------------------------
// Kernel 1: per-block partial channel sums + last-block finishes the
// reduction and computes per-batch rotation params (no separate dispatch).
// Grid: 1024 blocks x 256. Which block is "last" varies run-to-run, but the
// final per-(b,c) sum order is fixed (s = 0..127, double) -> bitwise
// deterministic output regardless.
// ---------------------------------------------------------------------------
__global__ __launch_bounds__(256) void reduce_angle_kernel(
        const float* __restrict__ x,
        const float* __restrict__ w_angle,
        const float* __restrict__ b_angle,
        unsigned* __restrict__ counter,
        float* __restrict__ partial,
        float* __restrict__ params) {
    const int bid = blockIdx.x;
    const int b   = bid & 7;
    const int s   = bid >> 3;
    const int tid = threadIdx.x;

    // ---- partial sum over this block's 128 KB slice ----
    const float4* xp = (const float4*)(x + (size_t)b * PIXELS * CH);
    int idx = s * 8192 + tid;            // 8192 float4 per slice
    float4 acc = make_float4(0.f, 0.f, 0.f, 0.f);
#pragma unroll 8
    for (int k = 0; k < 32; ++k) {
        float4 v = xp[idx + k * 256];
        acc.x += v.x; acc.y += v.y; acc.z += v.z; acc.w += v.w;
    }
    // reduce across lanes sharing (lane & 3); channel quad = lane&3
    for (int off = 4; off < 64; off <<= 1) {
        acc.x += __shfl_xor(acc.x, off);
        acc.y += __shfl_xor(acc.y, off);
        acc.z += __shfl_xor(acc.z, off);
        acc.w += __shfl_xor(acc.w, off);
    }
    __shared__ float swave[4][CH];
    const int wave = tid >> 6;
    const int lane = tid & 63;
    if (lane < 4) {
        swave[wave][lane * 4 + 0] = acc.x;
        swave[wave][lane * 4 + 1] = acc.y;
        swave[wave][lane * 4 + 2] = acc.z;
        swave[wave][lane * 4 + 3] = acc.w;
    }
    __syncthreads();
    if (tid < CH) {
        float t = swave[0][tid] + swave[1][tid]
                + swave[2][tid] + swave[3][tid];
        partial[(size_t)((b * SLICES + s) * CH) + tid] = t;
    }
    __syncthreads();

    // ---- last block finishes ----
    __shared__ unsigned ticket;
    if (tid == 0) {
        __threadfence();                       // release partials
        ticket = atomicAdd(counter, 1u);
    }
    __syncthreads();
    if (ticket != NBLK - 1) return;
    __threadfence();                           // acquire all partials

    __shared__ double mean_s[BATCH][CH];
    if (tid < BATCH * CH) {
        const int bb = tid >> 4;
        const int c  = tid & 15;
        double sum = 0.0;
        for (int ss = 0; ss < SLICES; ++ss)
            sum += (double)partial[(size_t)((bb * SLICES + ss) * CH) + c];
        mean_s[bb][c] = sum * (1.0 / (double)PIXELS);
    }
    __syncthreads();
    if (tid < BATCH) {
        double dot = 0.0;
#pragma unroll
        for (int c = 0; c < CH; ++c) dot += mean_s[tid][c] * (double)w_angle[c];
        double tn = tanh(dot + (double)b_angle[0]);
        const double pi = 3.14159265358979323846;
        double ang = fmin(fmax(tn * pi, -pi), pi);
        double cs = cos(ang);
        double sn = sin(ang);
        double x_off = (511.0 - (cs * 511.0 - sn * 511.0)) * 0.5;
        double y_off = (511.0 - (sn * 511.0 + cs * 511.0)) * 0.5;
        params[tid * 4 + 0] = (float)cs;
        params[tid * 4 + 1] = (float)sn;
        params[tid * 4 + 2] = (float)x_off;
        params[tid * 4 + 3] = (float)y_off;
    }
}

// ---------------------------------------------------------------------------
// Kernel 2: bilinear rotation gather. 4 threads per output pixel, one float4
// (4 channels) each. b = blockIdx.x & 7 is block-uniform (scalar param loads).
// XCD swizzle: each XCD (bid%8) owns one image in row order -> bilinear
// row-overlap stays in that XCD's private L2. NT stores keep x L2/L3-hot.
// ---------------------------------------------------------------------------
__global__ __launch_bounds__(256) void rotate_kernel(
        const float* __restrict__ x, const float* __restrict__ params,
        float* __restrict__ out) {
    const int bid  = blockIdx.x;
    const int b    = bid & 7;            // batch == XCD (scalar)
    const int sblk = bid >> 3;           // block within image, 0..4095
    const int tid  = threadIdx.x;
    const int gl   = sblk * 256 + tid;   // float4 index within image
    const int q    = gl & 3;             // channel quad
    const int p    = gl >> 2;            // pixel within image
    const int oy   = p >> 9;
    const int ox   = p & (HW - 1);

    const float cs = params[b * 4 + 0];
    const float sn = params[b * 4 + 1];
    const float xo = params[b * 4 + 2];
    const float yo = params[b * 4 + 3];

    const float fx = (float)ox;
    const float fy = (float)oy;
    const float ix = cs * fx - sn * fy + xo;
    const float iy = sn * fx + cs * fy + yo;
    const float x0f = floorf(ix);
    const float y0f = floorf(iy);
    const float wx = ix - x0f;
    const float wy = iy - y0f;
    const int x0 = (int)x0f;
    const int y0 = (int)y0f;

    const float4* base = (const float4*)x + (size_t)b * PIXELS * 4 + q;

    float4 v00, v01, v10, v11;
    if (x0 >= 0 && y0 >= 0 && x0 < HW - 1 && y0 < HW - 1) {
        // interior: all four taps valid (overwhelmingly common)
        const float4* row0 = base + (size_t)y0 * (HW * 4);
        v00 = row0[(size_t)x0 * 4];
        v01 = row0[(size_t)(x0 + 1) * 4];
        const float4* row1 = row0 + HW * 4;
        v10 = row1[(size_t)x0 * 4];
        v11 = row1[(size_t)(x0 + 1) * 4];
    } else {
        auto read = [&](int yy, int xx) -> float4 {
            if ((unsigned)xx < (unsigned)HW && (unsigned)yy < (unsigned)HW)
                return base[((size_t)yy * HW + xx) * 4];
            return make_float4(0.f, 0.f, 0.f, 0.f);
        };
        v00 = read(y0,     x0);
        v01 = read(y0,     x0 + 1);
        v10 = read(y0 + 1, x0);
        v11 = read(y0 + 1, x0 + 1);
    }

    const float wx1 = 1.0f - wx;
    const float wy1 = 1.0f - wy;
    f32x4 r;
    r.x = (v00.x * wx1 + v01.x * wx) * wy1 + (v10.x * wx1 + v11.x * wx) * wy;
    r.y = (v00.y * wx1 + v01.y * wx) * wy1 + (v10.y * wx1 + v11.y * wx) * wy;
    r.z = (v00.z * wx1 + v01.z * wx) * wy1 + (v10.z * wx1 + v11.z * wx) * wy;
    r.w = (v00.w * wx1 + v01.w * wx) * wy1 + (v10.w * wx1 + v11.w * wx) * wy;

    __builtin_nontemporal_store(r, (f32x4*)out + (size_t)b * PIXELS * 4 + gl);
}

extern "C" void kernel_launch(void* const* d_in, const int* in_sizes, int n_in,
                              void* d_out, int out_size, void* d_ws, size_t ws_size,
                              hipStream_t stream) {
    const float* x       = (const float*)d_in[0];
    const float* w_angle = (const float*)d_in[1];
    const float* b_angle = (const float*)d_in[2];
    float* out = (float*)d_out;

    // ws layout: [counter (16B-aligned slot)] [partial 16384 f] [params 32 f]
    unsigned* counter = (unsigned*)d_ws;
    float* partial = (float*)d_ws + 16;
    float* params  = partial + NBLK * CH;

    hipMemsetAsync(counter, 0, sizeof(unsigned), stream);
    reduce_angle_kernel<<<NBLK, 256, 0, stream>>>(x, w_angle, b_angle,
                                                  counter, partial, params);
    rotate_kernel<<<BATCH * PIXELS * 4 / 256, 256, 0, stream>>>(x, params, out);
}

// Round 6
// 71.108 us; speedup vs baseline: 4.1171x; 1.4292x over previous
//
#include <hip/hip_runtime.h>
#include <math.h>

#define HW     512
#define CH     16
#define PIXELS (HW * HW)          // 262144 = 2^18
#define BATCH  8
#define RED_SLICES 128            // blocks per batch in reduction

typedef float f32x4 __attribute__((ext_vector_type(4)));

// ---------------------------------------------------------------------------
// Kernel 1: per-block partial channel sums (identical to R3 — proven).
// Grid: BATCH * RED_SLICES = 1024 blocks, 256 threads. No fences, no atomics.
// Normal (caching) loads on purpose: leaves x resident in L3 for the rotate.
// ---------------------------------------------------------------------------
__global__ __launch_bounds__(256) void reduce_partial_kernel(
        const float* __restrict__ x, float* __restrict__ partial) {
    const int b = blockIdx.x >> 7;          // / RED_SLICES
    const int s = blockIdx.x & (RED_SLICES - 1);
    const float4* xp = (const float4*)(x + (size_t)b * PIXELS * CH);
    // float4s per batch = 1048576; per block = 8192; per thread = 32
    int idx = s * 8192 + threadIdx.x;
    float4 acc = make_float4(0.f, 0.f, 0.f, 0.f);
#pragma unroll 8
    for (int k = 0; k < 32; ++k) {
        float4 v = xp[idx + k * 256];
        acc.x += v.x; acc.y += v.y; acc.z += v.z; acc.w += v.w;
    }
    // reduce across the 16 lanes sharing (lane & 3): channel quad is lane&3
    for (int off = 4; off < 64; off <<= 1) {
        acc.x += __shfl_xor(acc.x, off);
        acc.y += __shfl_xor(acc.y, off);
        acc.z += __shfl_xor(acc.z, off);
        acc.w += __shfl_xor(acc.w, off);
    }
    __shared__ float swave[4][CH];
    const int wave = threadIdx.x >> 6;
    const int lane = threadIdx.x & 63;
    if (lane < 4) {
        swave[wave][lane * 4 + 0] = acc.x;
        swave[wave][lane * 4 + 1] = acc.y;
        swave[wave][lane * 4 + 2] = acc.z;
        swave[wave][lane * 4 + 3] = acc.w;
    }
    __syncthreads();
    if (threadIdx.x < CH) {
        float t = swave[0][threadIdx.x] + swave[1][threadIdx.x]
                + swave[2][threadIdx.x] + swave[3][threadIdx.x];
        partial[(size_t)blockIdx.x * CH + threadIdx.x] = t;
    }
}

// ---------------------------------------------------------------------------
// Kernel 2: finish reduction + per-batch rotation params (identical to R3).
// ---------------------------------------------------------------------------
__global__ void angle_kernel(const float* __restrict__ partial,
                             const float* __restrict__ w_angle,
                             const float* __restrict__ b_angle,
                             float* __restrict__ params) {
    __shared__ double mean_s[BATCH][CH];
    const int t = threadIdx.x;
    if (t < BATCH * CH) {
        const int b = t >> 4;
        const int c = t & 15;
        double sum = 0.0;
        for (int s = 0; s < RED_SLICES; ++s)
            sum += (double)partial[(size_t)(b * RED_SLICES + s) * CH + c];
        mean_s[b][c] = sum * (1.0 / (double)PIXELS);
    }
    __syncthreads();
    if (t < BATCH) {
        double dot = 0.0;
        for (int c = 0; c < CH; ++c) dot += mean_s[t][c] * (double)w_angle[c];
        double tn = tanh(dot + (double)b_angle[0]);
        const double pi = 3.14159265358979323846;
        double ang = fmin(fmax(tn * pi, -pi), pi);
        double cs = cos(ang);
        double sn = sin(ang);
        double x_off = (511.0 - (cs * 511.0 - sn * 511.0)) * 0.5;
        double y_off = (511.0 - (sn * 511.0 + cs * 511.0)) * 0.5;
        params[t * 4 + 0] = (float)cs;
        params[t * 4 + 1] = (float)sn;
        params[t * 4 + 2] = (float)x_off;
        params[t * 4 + 3] = (float)y_off;
    }
}

// ---------------------------------------------------------------------------
// Kernel 3: bilinear rotation gather. 2 float4s (pixel-quads) per thread for
// ILP: 8 independent loads + 2 NT stores in flight. b = blockIdx.x & 7 is
// block-uniform -> scalar param loads. XCD (bid%8) owns one image -> bilinear
// row-overlap stays in its private L2. NT stores keep x L2/L3-resident.
// Grid: BATCH*PIXELS*4/512 = 16384 blocks, 256 threads.
// ---------------------------------------------------------------------------
__global__ __launch_bounds__(256) void rotate_kernel(
        const float* __restrict__ x, const float* __restrict__ params,
        float* __restrict__ out) {
    const int bid  = blockIdx.x;
    const int b    = bid & 7;            // batch == XCD (block-uniform)
    const int sblk = bid >> 3;           // 0..2047 within image
    const int tid  = threadIdx.x;

    const float cs = params[b * 4 + 0];
    const float sn = params[b * 4 + 1];
    const float xo = params[b * 4 + 2];
    const float yo = params[b * 4 + 3];

    const float4* base = (const float4*)x + (size_t)b * PIXELS * 4;
    float4*       obase = (float4*)out    + (size_t)b * PIXELS * 4;

#pragma unroll
    for (int half = 0; half < 2; ++half) {
        const int gl = sblk * 512 + half * 256 + tid;  // float4 idx in image
        const int q  = gl & 3;                         // channel quad
        const int p  = gl >> 2;                        // pixel in image
        const int oy = p >> 9;
        const int ox = p & (HW - 1);

        const float fx = (float)ox;
        const float fy = (float)oy;
        const float ix = cs * fx - sn * fy + xo;
        const float iy = sn * fx + cs * fy + yo;
        const int x0 = __float2int_rd(ix);   // floor
        const int y0 = __float2int_rd(iy);
        const float wx = ix - (float)x0;
        const float wy = iy - (float)y0;

        const float4* bq = base + q;
        float4 v00, v01, v10, v11;
        if (x0 >= 0 && y0 >= 0 && x0 < HW - 1 && y0 < HW - 1) {
            const float4* row0 = bq + (size_t)y0 * (HW * 4);
            v00 = row0[(size_t)x0 * 4];
            v01 = row0[(size_t)(x0 + 1) * 4];
            const float4* row1 = row0 + HW * 4;
            v10 = row1[(size_t)x0 * 4];
            v11 = row1[(size_t)(x0 + 1) * 4];
        } else {
            auto read = [&](int yy, int xx) -> float4 {
                if ((unsigned)xx < (unsigned)HW && (unsigned)yy < (unsigned)HW)
                    return bq[((size_t)yy * HW + xx) * 4];
                return make_float4(0.f, 0.f, 0.f, 0.f);
            };
            v00 = read(y0,     x0);
            v01 = read(y0,     x0 + 1);
            v10 = read(y0 + 1, x0);
            v11 = read(y0 + 1, x0 + 1);
        }

        const float wx1 = 1.0f - wx;
        const float wy1 = 1.0f - wy;
        f32x4 r;
        r.x = (v00.x * wx1 + v01.x * wx) * wy1 + (v10.x * wx1 + v11.x * wx) * wy;
        r.y = (v00.y * wx1 + v01.y * wx) * wy1 + (v10.y * wx1 + v11.y * wx) * wy;
        r.z = (v00.z * wx1 + v01.z * wx) * wy1 + (v10.z * wx1 + v11.z * wx) * wy;
        r.w = (v00.w * wx1 + v01.w * wx) * wy1 + (v10.w * wx1 + v11.w * wx) * wy;

        __builtin_nontemporal_store(r, (f32x4*)(obase + gl));
    }
}

extern "C" void kernel_launch(void* const* d_in, const int* in_sizes, int n_in,
                              void* d_out, int out_size, void* d_ws, size_t ws_size,
                              hipStream_t stream) {
    const float* x       = (const float*)d_in[0];
    const float* w_angle = (const float*)d_in[1];
    const float* b_angle = (const float*)d_in[2];
    float* out = (float*)d_out;

    float* partial = (float*)d_ws;                                 // 16384 f
    float* params  = partial + BATCH * RED_SLICES * CH;            // 32 f

    reduce_partial_kernel<<<BATCH * RED_SLICES, 256, 0, stream>>>(x, partial);
    angle_kernel<<<1, 128, 0, stream>>>(partial, w_angle, b_angle, params);
    rotate_kernel<<<BATCH * PIXELS * 4 / 512, 256, 0, stream>>>(x, params, out);
}

// Round 7
// 66.621 us; speedup vs baseline: 4.3944x; 1.0674x over previous
//
#include <hip/hip_runtime.h>
#include <math.h>

#define HW     512
#define CH     16
#define PIXELS (HW * HW)          // 262144 = 2^18
#define BATCH  8
#define RED_SLICES 128            // blocks per batch in reduction

typedef float f32x4 __attribute__((ext_vector_type(4)));

// ---------------------------------------------------------------------------
// Kernel 1: per-block partial channel sums (identical to R3 — proven).
// Grid: BATCH * RED_SLICES = 1024 blocks, 256 threads. No fences, no atomics.
// Normal (caching) loads on purpose: leaves x resident in L3 for the rotate.
// Layout: partial[(b*128+s)*16 + c].
// ---------------------------------------------------------------------------
__global__ __launch_bounds__(256) void reduce_partial_kernel(
        const float* __restrict__ x, float* __restrict__ partial) {
    const int b = blockIdx.x >> 7;          // / RED_SLICES
    const int s = blockIdx.x & (RED_SLICES - 1);
    const float4* xp = (const float4*)(x + (size_t)b * PIXELS * CH);
    // float4s per batch = 1048576; per block = 8192; per thread = 32
    int idx = s * 8192 + threadIdx.x;
    float4 acc = make_float4(0.f, 0.f, 0.f, 0.f);
#pragma unroll 8
    for (int k = 0; k < 32; ++k) {
        float4 v = xp[idx + k * 256];
        acc.x += v.x; acc.y += v.y; acc.z += v.z; acc.w += v.w;
    }
    // reduce across the 16 lanes sharing (lane & 3): channel quad is lane&3
    for (int off = 4; off < 64; off <<= 1) {
        acc.x += __shfl_xor(acc.x, off);
        acc.y += __shfl_xor(acc.y, off);
        acc.z += __shfl_xor(acc.z, off);
        acc.w += __shfl_xor(acc.w, off);
    }
    __shared__ float swave[4][CH];
    const int wave = threadIdx.x >> 6;
    const int lane = threadIdx.x & 63;
    if (lane < 4) {
        swave[wave][lane * 4 + 0] = acc.x;
        swave[wave][lane * 4 + 1] = acc.y;
        swave[wave][lane * 4 + 2] = acc.z;
        swave[wave][lane * 4 + 3] = acc.w;
    }
    __syncthreads();
    if (threadIdx.x < CH) {
        float t = swave[0][threadIdx.x] + swave[1][threadIdx.x]
                + swave[2][threadIdx.x] + swave[3][threadIdx.x];
        partial[(size_t)blockIdx.x * CH + threadIdx.x] = t;
    }
}

// ---------------------------------------------------------------------------
// Kernel 2: angle prologue (per-block, redundant, L2-hot) + bilinear rotate.
// Grid: 32768 blocks x 256 (R3's proven best gather shape: 1 float4/thread).
// b = bid & 7 -> XCD (bid%8) owns one image: prologue partials (8 KB/batch)
// and bilinear row-overlap both stay in that XCD's private L2.
// Prologue reduction order is fixed (sg + 16j grouping, then 16-way tree) ->
// bitwise deterministic across blocks and replays.
// ---------------------------------------------------------------------------
__global__ __launch_bounds__(256) void rotate_kernel(
        const float* __restrict__ x,
        const float* __restrict__ w_angle,
        const float* __restrict__ b_angle,
        const float* __restrict__ partial,
        float* __restrict__ out) {
    const int bid  = blockIdx.x;
    const int b    = bid & 7;            // batch == XCD (block-uniform)
    const int sblk = bid >> 3;           // 0..4095 within image
    const int tid  = threadIdx.x;

    __shared__ float red[16][CH];
    __shared__ float prm[4];

    // ---- prologue: this batch's rotation params from partials ----
    {
        const int c  = tid & 15;
        const int sg = tid >> 4;         // 0..15
        float s8 = 0.f;
#pragma unroll
        for (int j = 0; j < 8; ++j)
            s8 += partial[(size_t)((b * RED_SLICES + sg + 16 * j) * CH) + c];
        red[sg][c] = s8;
        __syncthreads();
        if (tid < CH) {
            float m = 0.f;
#pragma unroll
            for (int g = 0; g < 16; ++g) m += red[g][tid];
            red[0][tid] = m * (1.0f / (float)PIXELS);   // mean_c
        }
        __syncthreads();
        if (tid == 0) {
            float dot = b_angle[0];
#pragma unroll
            for (int c2 = 0; c2 < CH; ++c2) dot += red[0][c2] * w_angle[c2];
            float tn = tanhf(dot);
            const float pi = 3.14159265358979323846f;
            float ang = fminf(fmaxf(tn * pi, -pi), pi);
            float cs = cosf(ang);
            float sn = sinf(ang);
            prm[0] = cs;
            prm[1] = sn;
            prm[2] = (511.0f - (cs * 511.0f - sn * 511.0f)) * 0.5f;  // x_off
            prm[3] = (511.0f - (sn * 511.0f + cs * 511.0f)) * 0.5f;  // y_off
        }
        __syncthreads();
    }

    const float cs = prm[0];
    const float sn = prm[1];
    const float xo = prm[2];
    const float yo = prm[3];

    // ---- gather: 1 float4 (4 channels) per thread ----
    const int gl = sblk * 256 + tid;     // float4 index within image
    const int q  = gl & 3;               // channel quad
    const int p  = gl >> 2;              // pixel within image
    const int oy = p >> 9;
    const int ox = p & (HW - 1);

    const float fx = (float)ox;
    const float fy = (float)oy;
    const float ix = cs * fx - sn * fy + xo;
    const float iy = sn * fx + cs * fy + yo;
    const int x0 = __float2int_rd(ix);   // floor
    const int y0 = __float2int_rd(iy);
    const float wx = ix - (float)x0;
    const float wy = iy - (float)y0;

    const float4* base = (const float4*)x + (size_t)b * PIXELS * 4 + q;

    float4 v00, v01, v10, v11;
    if (x0 >= 0 && y0 >= 0 && x0 < HW - 1 && y0 < HW - 1) {
        // interior: all four taps valid (overwhelmingly common)
        const float4* row0 = base + (size_t)y0 * (HW * 4);
        v00 = row0[(size_t)x0 * 4];
        v01 = row0[(size_t)(x0 + 1) * 4];
        const float4* row1 = row0 + HW * 4;
        v10 = row1[(size_t)x0 * 4];
        v11 = row1[(size_t)(x0 + 1) * 4];
    } else {
        auto read = [&](int yy, int xx) -> float4 {
            if ((unsigned)xx < (unsigned)HW && (unsigned)yy < (unsigned)HW)
                return base[((size_t)yy * HW + xx) * 4];
            return make_float4(0.f, 0.f, 0.f, 0.f);
        };
        v00 = read(y0,     x0);
        v01 = read(y0,     x0 + 1);
        v10 = read(y0 + 1, x0);
        v11 = read(y0 + 1, x0 + 1);
    }

    const float wx1 = 1.0f - wx;
    const float wy1 = 1.0f - wy;
    f32x4 r;
    r.x = (v00.x * wx1 + v01.x * wx) * wy1 + (v10.x * wx1 + v11.x * wx) * wy;
    r.y = (v00.y * wx1 + v01.y * wx) * wy1 + (v10.y * wx1 + v11.y * wx) * wy;
    r.z = (v00.z * wx1 + v01.z * wx) * wy1 + (v10.z * wx1 + v11.z * wx) * wy;
    r.w = (v00.w * wx1 + v01.w * wx) * wy1 + (v10.w * wx1 + v11.w * wx) * wy;

    __builtin_nontemporal_store(r, (f32x4*)out + (size_t)b * PIXELS * 4 + gl);
}

extern "C" void kernel_launch(void* const* d_in, const int* in_sizes, int n_in,
                              void* d_out, int out_size, void* d_ws, size_t ws_size,
                              hipStream_t stream) {
    const float* x       = (const float*)d_in[0];
    const float* w_angle = (const float*)d_in[1];
    const float* b_angle = (const float*)d_in[2];
    float* out = (float*)d_out;

    float* partial = (float*)d_ws;       // BATCH*RED_SLICES*CH = 16384 floats

    reduce_partial_kernel<<<BATCH * RED_SLICES, 256, 0, stream>>>(x, partial);
    rotate_kernel<<<BATCH * PIXELS * 4 / 256, 256, 0, stream>>>(
        x, w_angle, b_angle, partial, out);
}